// Round 7
// baseline (185.302 us; speedup 1.0000x reference)
//
#include <hip/hip_runtime.h>
#include <hip/hip_bf16.h>

// Problem dims (fixed by setup_inputs):
//   B=4, S=2048, H=1024, NH=16, D=64, M = B*S = 8192
#define S_LEN   2048
#define NHEADS  16
#define HDIM    64
#define HID     1024
#define BATCH   4
#define M_ROWS  (BATCH * S_LEN)   // 8192

typedef __attribute__((ext_vector_type(8))) short short8;
typedef __attribute__((ext_vector_type(4))) float floatx4;   // clang vector (NT-builtin OK)
typedef __attribute__((ext_vector_type(4))) unsigned short ushort4v;

__device__ __forceinline__ unsigned short f2bf_rne(float x) {
  union { float f; unsigned u; } v; v.f = x;
  unsigned r = v.u + 0x7fffu + ((v.u >> 16) & 1u);
  return (unsigned short)(r >> 16);
}

__device__ __forceinline__ float bf2f(unsigned short u) {
  union { unsigned u; float f; } c; c.u = ((unsigned)u) << 16;
  return c.f;
}

__device__ __forceinline__ void glds16(const unsigned short* g, unsigned short* l) {
  __builtin_amdgcn_global_load_lds(
      (const __attribute__((address_space(1))) unsigned int*)g,
      (__attribute__((address_space(3))) unsigned int*)l, 16, 0, 0);
}

// ---------------- fp32 -> bf16 cast, all 4 tensors in one dispatch ----------
#define HS4 (M_ROWS * HID / 4)        // 2097152
#define W4  (HID * HID / 4)           // 262144
__global__ __launch_bounds__(256) void cast_all(
    const float* __restrict__ hs, const float* __restrict__ Wq,
    const float* __restrict__ Wk, const float* __restrict__ Wv,
    unsigned short* __restrict__ hsb, unsigned short* __restrict__ wqb,
    unsigned short* __restrict__ wkb, unsigned short* __restrict__ wvb) {
  int idx = blockIdx.x * 256 + threadIdx.x;
  const float* in;
  unsigned short* out;
  int off;
  if (idx < HS4) {
    in = hs; out = hsb; off = idx;
  } else {
    int r = idx - HS4;
    int seg = r >> 18;          // W4 = 2^18
    off = r & (W4 - 1);
    in  = (seg == 0) ? Wq  : (seg == 1) ? Wk  : Wv;
    out = (seg == 0) ? wqb : (seg == 1) ? wkb : wvb;
  }
  // fp32 inputs are read exactly once -> non-temporal (don't pollute L2)
  floatx4 v = __builtin_nontemporal_load((const floatx4*)in + off);
  ushort4v o;
  o.x = f2bf_rne(v.x);
  o.y = f2bf_rne(v.y);
  o.z = f2bf_rne(v.z);
  o.w = f2bf_rne(v.w);
  ((ushort4v*)out)[off] = o;
}

// ---------------- QKV projection GEMM (R7: half-K ring-4 pipeline) ---------
// C[m,n] = bf16(sum_k A[m,k]*W[n,k] + bias[n]); A: MxK bf16, W: NxK bf16.
// Tile 256x128, 512 threads = 8 waves (4M x 2N), per-wave 64x64 via 4x4
// MFMA 16x16x32 fragments. Dataflow/map/epilogue = R2 (verified).
//
// R6 analysis: R2's 2980cyc/K-tile vs ~900cyc resource need (reads 512 +
// MFMA 307 + writes ~380 @ 256B/cyc LDS) => ~2000cyc/tile is LOCKSTEP STALL
// (m233: stage+vmcnt+barrier = 72% of 2-phase loops), not LDS throughput.
// R7 shrinks the sync quantum: K-step = 32 (32 halves), LDS = ring of FOUR
// 24KB half-slots (96KB). Per half: {vmcnt(6) counted -> barrier ->
// issue 3 glds for half h+3 -> 8 ds_read_b128 -> 16 MFMA}. One barrier per
// half, prefetch distance 3 halves, vmcnt counted (6) until the tail
// (h=30 -> 3, h=31 -> 0). Race safety: slot (h+3)&3 == (h-1)&3 is written
// only by glds issued after the half-h barrier; all waves reached it only
// after their half-(h-1) reads were consumed (compiler lgkmcnt before MFMA).
//
// Swizzle (32-elem rows = 4 chunks of 16B, R5-verified 0 conflicts):
// stage: lane l -> row lr=l>>2, LDS chunk l&3, global chunk (l&3)^((lr>>1)&3);
// read: chunk qd^((lrow>>1)&3).
// Block->work map (verified R2: FETCH 49MB): XCD-round = 4-mtile x 8-slab
// superblock -> A 2MB + one Wz 2MB = 4MB per-XCD L2. Grid 768 = 3 rounds.
__global__ __launch_bounds__(512, 2) void qkv_gemm(
    const unsigned short* __restrict__ A,
    const unsigned short* __restrict__ W0, const unsigned short* __restrict__ W1,
    const unsigned short* __restrict__ W2,
    const float* __restrict__ b0, const float* __restrict__ b1,
    const float* __restrict__ b2,
    unsigned short* __restrict__ O0, unsigned short* __restrict__ O1,
    unsigned short* __restrict__ O2) {
  const int K = HID;
  const int N = HID;

  __shared__ __align__(16) unsigned short lds[4 * 12288];  // 4 x 24 KB ring

  const int tid = threadIdx.x;
  const int w = tid >> 6;          // 0..7
  const int lane = tid & 63;

  // XCD-local superblock mapping (verified R2: FETCH 49MB).
  const int bid = blockIdx.x;
  const int xcd = bid & 7;
  const int rr  = bid >> 3;        // 0..95
  const int sb  = rr >> 5;         // 0..2  XCD-round
  const int q   = rr & 31;
  const int sbid = xcd * 3 + sb;   // 0..23
  const int mg = sbid & 7;
  const int sg = sbid >> 3;
  const int mi   = mg * 4 + (q & 3);    // 0..31
  const int slab = sg * 8 + (q >> 2);   // 0..23 = z*8 + ni
  const int ni = slab & 7;
  const int z  = slab >> 3;
  const int m0 = mi << 8;          // *256
  const int n0 = ni << 7;          // *128

  const unsigned short* __restrict__ Wz = (z == 0) ? W0 : (z == 1) ? W1 : W2;
  const float* __restrict__ bias = (z == 0) ? b0 : (z == 1) ? b1 : b2;
  unsigned short* __restrict__ O = (z == 0) ? O0 : (z == 1) ? O1 : O2;

  // staging: per K-half 24 KB = 24 segments of 1 KB (16 rows x 4 chunks of
  // 16B). Wave w owns segments w*3+u (u=0..2): segs 0..15 = A (256 rows),
  // segs 16..23 = B (128 rows). Lane l -> row lr=l>>2, LDS chunk l&3,
  // global chunk (l&3)^((lr>>1)&3) (source-side swizzle, LDS stays linear).
  const int lr = lane >> 2;
  const int gc = (lane & 3) ^ ((lr >> 1) & 3);
  const unsigned short* gsrc[3];
  unsigned short* ldst[3];
  #pragma unroll
  for (int u = 0; u < 3; ++u) {
    const int seg = w * 3 + u;
    if (seg < 16) {
      gsrc[u] = A + (size_t)(m0 + seg * 16 + lr) * K + gc * 8;
    } else {
      gsrc[u] = Wz + (size_t)(n0 + (seg - 16) * 16 + lr) * K + gc * 8;
    }
    ldst[u] = lds + seg * 512;
  }

  // stage one K-half into ring slot h&3: 3 glds16/thread (vmcnt unit = 3)
  auto stage = [&](int h) {
    const int bofs = (h & 3) * 12288;
    const int ko = h * 32;
    #pragma unroll
    for (int u = 0; u < 3; ++u)
      glds16(gsrc[u] + ko, ldst[u] + bofs);
  };

  const int lrow = lane & 15;
  const int qd = lane >> 4;                    // 0..3
  const int cp = (qd ^ ((lrow >> 1) & 3)) * 8; // swizzled chunk -> shorts
  const int arow = (w & 3) * 64 + lrow;        // wave m-offset
  const int brow = (w >> 2) * 64 + lrow;       // wave n-offset

  floatx4 acc[4][4] = {};

  auto half_body = [&](int h, bool pf) {
    const unsigned short* Asb = lds + (h & 3) * 12288;
    const unsigned short* Bsb = Asb + 8192;
    if (pf) stage(h + 3);              // issue-early: in flight 3 halves
    short8 af[4], bf[4];
    #pragma unroll
    for (int im = 0; im < 4; ++im)
      af[im] = *(const short8*)(Asb + (arow + im * 16) * 32 + cp);
    #pragma unroll
    for (int in = 0; in < 4; ++in)
      bf[in] = *(const short8*)(Bsb + (brow + in * 16) * 32 + cp);
    __builtin_amdgcn_s_setprio(1);
    #pragma unroll
    for (int im = 0; im < 4; ++im)
      #pragma unroll
      for (int in = 0; in < 4; ++in)
        acc[im][in] = __builtin_amdgcn_mfma_f32_16x16x32_bf16(af[im], bf[in], acc[im][in], 0, 0, 0);
    __builtin_amdgcn_s_setprio(0);
  };

  // prologue: halves 0,1,2 in flight (9 loads/thread outstanding)
  stage(0); stage(1); stage(2);

  #pragma unroll 4
  for (int h = 0; h < 29; ++h) {
    // counted wait: half h landed; halves h+1,h+2 (6 loads) stay in flight
    asm volatile("s_waitcnt vmcnt(6)" ::: "memory");
    __builtin_amdgcn_s_barrier();
    asm volatile("" ::: "memory");
    half_body(h, true);
  }
  // tail: no more staging; drain counted
  asm volatile("s_waitcnt vmcnt(6)" ::: "memory");
  __builtin_amdgcn_s_barrier();
  asm volatile("" ::: "memory");
  half_body(29, false);
  asm volatile("s_waitcnt vmcnt(3)" ::: "memory");
  __builtin_amdgcn_s_barrier();
  asm volatile("" ::: "memory");
  half_body(30, false);
  asm volatile("s_waitcnt vmcnt(0)" ::: "memory");
  __builtin_amdgcn_s_barrier();
  asm volatile("" ::: "memory");
  half_body(31, false);

  // epilogue: C/D layout col = lane&15, row = quad*4 + r; write bf16
  #pragma unroll
  for (int im = 0; im < 4; ++im) {
    #pragma unroll
    for (int in = 0; in < 4; ++in) {
      const int col = n0 + (w >> 2) * 64 + in * 16 + lrow;
      const float bb = bias[col];
      #pragma unroll
      for (int r = 0; r < 4; ++r) {
        const int row = m0 + (w & 3) * 64 + im * 16 + (qd << 2) + r;
        O[(size_t)row * N + col] = f2bf_rne(acc[im][in][r] + bb);
      }
    }
  }
}

// ---------------- log-sparse attention ----------------
// 8 lanes per query (lane = 8 dims, 16 B bf16 loads), 32 queries per block.
// Two-phase register budget (K+scores+softmax, then V+accumulate).
// XCD-contiguous block swizzle: blocks for one head stay on one XCD's L2.
// Non-temporal output stores: out (32 MB, never re-read) must not evict the
// K/V gather working set from L2.
__global__ __launch_bounds__(256) void logsparse_attn(
    const unsigned short* __restrict__ Q, const unsigned short* __restrict__ K,
    const unsigned short* __restrict__ V, const float* __restrict__ mask,
    float* __restrict__ out) {
  // 4096 blocks -> XCD x gets contiguous logical range [x*512, (x+1)*512)
  const int bid = (blockIdx.x & 7) * 512 + (blockIdx.x >> 3);
  const int tid = threadIdx.x;
  const int l = tid & 7;
  const int qglob = bid * 32 + (tid >> 3);

  const int i = qglob & (S_LEN - 1);
  const int h = (qglob >> 11) & (NHEADS - 1);
  const int b = qglob >> 15;

  const size_t base = (size_t)b * S_LEN * HID + h * HDIM + l * 8;

  int js[12];
  js[0] = i;
  int nj = 1;
  for (int d = 1; d <= i; d <<= 1) js[nj++] = i - d;
  #pragma unroll
  for (int t = 0; t < 12; ++t)
    if (t >= nj) js[t] = i;   // clamp: valid row, zeroed after mask

  // ---- phase 1: K + Q + mask prefetch, scores, softmax ----
  short8 k8[12];
  #pragma unroll
  for (int t = 0; t < 12; ++t)
    k8[t] = *(const short8*)(K + base + (size_t)js[t] * HID);
  const short8 q8 = *(const short8*)(Q + base + (size_t)i * HID);
  float mk[12];
  #pragma unroll
  for (int t = 0; t < 12; ++t)
    mk[t] = mask[b * S_LEN + js[t]];

  float qf[8];
  #pragma unroll
  for (int e = 0; e < 8; ++e) qf[e] = bf2f((unsigned short)q8[e]);

  float s[12];
  #pragma unroll
  for (int t = 0; t < 12; ++t) {
    float p = 0.f;
    #pragma unroll
    for (int e = 0; e < 8; ++e) p += qf[e] * bf2f((unsigned short)k8[t][e]);
    p += __shfl_xor(p, 1, 64);
    p += __shfl_xor(p, 2, 64);
    p += __shfl_xor(p, 4, 64);
    s[t] = (t < nj) ? (p * 0.125f + mk[t]) : -1e30f;
  }

  float mx = s[0];
  #pragma unroll
  for (int t = 1; t < 12; ++t) mx = fmaxf(mx, s[t]);
  float lsum = 0.f;
  #pragma unroll
  for (int t = 0; t < 12; ++t) { s[t] = __expf(s[t] - mx); lsum += s[t]; }
  const float inv = 1.f / lsum;

  // ---- phase 2: V batch load + accumulate ----
  short8 v8[12];
  #pragma unroll
  for (int t = 0; t < 12; ++t)
    v8[t] = *(const short8*)(V + base + (size_t)js[t] * HID);

  float o[8] = {};
  #pragma unroll
  for (int t = 0; t < 12; ++t) {
    #pragma unroll
    for (int e = 0; e < 8; ++e) o[e] += s[t] * bf2f((unsigned short)v8[t][e]);
  }

  float* op = out + base + (size_t)i * HID;
  floatx4 o0 = {o[0] * inv, o[1] * inv, o[2] * inv, o[3] * inv};
  floatx4 o1 = {o[4] * inv, o[5] * inv, o[6] * inv, o[7] * inv};
  __builtin_nontemporal_store(o0, (floatx4*)op);
  __builtin_nontemporal_store(o1, (floatx4*)(op + 4));
}

// ---------------- launch ----------------
extern "C" void kernel_launch(void* const* d_in, const int* in_sizes, int n_in,
                              void* d_out, int out_size, void* d_ws, size_t ws_size,
                              hipStream_t stream) {
  const float* hs   = (const float*)d_in[0];
  const float* mask = (const float*)d_in[1];
  const float* Wq   = (const float*)d_in[2];
  const float* bq   = (const float*)d_in[3];
  const float* Wk   = (const float*)d_in[4];
  const float* bk   = (const float*)d_in[5];
  const float* Wv   = (const float*)d_in[6];
  const float* bv   = (const float*)d_in[7];
  float* out = (float*)d_out;

  // workspace layout (all bf16)
  unsigned short* hsb = (unsigned short*)d_ws;                  // M*H
  unsigned short* wqb = hsb + (size_t)M_ROWS * HID;             // H*H
  unsigned short* wkb = wqb + (size_t)HID * HID;
  unsigned short* wvb = wkb + (size_t)HID * HID;
  unsigned short* Qb = wvb + (size_t)HID * HID;                 // M*H
  unsigned short* Kb = Qb + (size_t)M_ROWS * HID;
  unsigned short* Vb = Kb + (size_t)M_ROWS * HID;

  // casts: one dispatch for hs + Wq + Wk + Wv
  {
    int quads = HS4 + 3 * W4;                 // 2883584
    cast_all<<<quads / 256, 256, 0, stream>>>(hs, Wq, Wk, Wv, hsb, wqb, wkb, wvb);
  }

  // QKV projections: 256x128 tiles -> 768 blocks = 3 rounds of 1 block/CU
  {
    qkv_gemm<<<768, 512, 0, stream>>>(hsb, wqb, wkb, wvb, bq, bk, bv, Qb, Kb, Vb);
  }

  // sparse attention: 32 queries per 256-thread block
  {
    int blocks = (BATCH * NHEADS * S_LEN) / 32;   // 4096
    logsparse_attn<<<blocks, 256, 0, stream>>>(Qb, Kb, Vb, mask, out);
  }
}

// Round 9
// 172.903 us; speedup vs baseline: 1.0717x; 1.0717x over previous
//
#include <hip/hip_runtime.h>
#include <hip/hip_bf16.h>

// Problem dims (fixed by setup_inputs):
//   B=4, S=2048, H=1024, NH=16, D=64, M = B*S = 8192
#define S_LEN   2048
#define NHEADS  16
#define HDIM    64
#define HID     1024
#define BATCH   4
#define M_ROWS  (BATCH * S_LEN)   // 8192

typedef __attribute__((ext_vector_type(8))) short short8;
typedef __attribute__((ext_vector_type(4))) float floatx4;   // clang vector (NT-builtin OK)
typedef __attribute__((ext_vector_type(4))) unsigned short ushort4v;

__device__ __forceinline__ unsigned short f2bf_rne(float x) {
  union { float f; unsigned u; } v; v.f = x;
  unsigned r = v.u + 0x7fffu + ((v.u >> 16) & 1u);
  return (unsigned short)(r >> 16);
}

__device__ __forceinline__ float bf2f(unsigned short u) {
  union { unsigned u; float f; } c; c.u = ((unsigned)u) << 16;
  return c.f;
}

__device__ __forceinline__ void glds16(const unsigned short* g, unsigned short* l) {
  __builtin_amdgcn_global_load_lds(
      (const __attribute__((address_space(1))) unsigned int*)g,
      (__attribute__((address_space(3))) unsigned int*)l, 16, 0, 0);
}

// ---------------- fp32 -> bf16 cast, all 4 tensors in one dispatch ----------
#define HS4 (M_ROWS * HID / 4)        // 2097152
#define W4  (HID * HID / 4)           // 262144
__global__ __launch_bounds__(256) void cast_all(
    const float* __restrict__ hs, const float* __restrict__ Wq,
    const float* __restrict__ Wk, const float* __restrict__ Wv,
    unsigned short* __restrict__ hsb, unsigned short* __restrict__ wqb,
    unsigned short* __restrict__ wkb, unsigned short* __restrict__ wvb) {
  int idx = blockIdx.x * 256 + threadIdx.x;
  const float* in;
  unsigned short* out;
  int off;
  if (idx < HS4) {
    in = hs; out = hsb; off = idx;
  } else {
    int r = idx - HS4;
    int seg = r >> 18;          // W4 = 2^18
    off = r & (W4 - 1);
    in  = (seg == 0) ? Wq  : (seg == 1) ? Wk  : Wv;
    out = (seg == 0) ? wqb : (seg == 1) ? wkb : wvb;
  }
  // fp32 inputs are read exactly once -> non-temporal (don't pollute L2)
  floatx4 v = __builtin_nontemporal_load((const floatx4*)in + off);
  ushort4v o;
  o.x = f2bf_rne(v.x);
  o.y = f2bf_rne(v.y);
  o.z = f2bf_rne(v.z);
  o.w = f2bf_rne(v.w);
  ((ushort4v*)out)[off] = o;
}

// ---------------- QKV projection GEMM (R2 config: best dispatch-verified) --
// C[m,n] = bf16(sum_k A[m,k]*W[n,k] + bias[n]); A: MxK bf16, W: NxK bf16.
// Tile 256x128, BK=64, 512 threads = 8 waves (4M x 2N), per-wave 64x64 via
// 4x4 MFMA 16x16x32 fragments (2 K-substeps per tile).
// Triple-buffered LDS (3 x 48 KB = 144 KB): while computing K-tile t we stage
// tile t+2; steady-state wait is s_waitcnt vmcnt(6) (tile t+1 stays in
// flight) + ONE raw s_barrier per K-tile — no vmcnt(0) drain in the loop.
// Race safety: stage(t+2) targets buf (t+2)%3 == buf (t-1)%3; the pre-barrier
// lgkmcnt(0) proves every wave drained its tile t-1 ds_reads first.
//
// MEASURED (R2/R6, reproducible): 59.0-59.7us, MfmaUtil ~35%, FETCH 49.2MB,
// 0 bank conflicts. Structural re-designs tried and REGRESSED (record; do
// not retry):
//   R3 phase-split+sched_barrier (61.4us): lockstep stall not schedule-bound
//   R4 256x256/BK=32, 384 blocks (70.3us): 1.5-round grid tail
//   R5 256x128/4-wave/BK=32 (76.9us): sync overhead doubled, no self-cover
//   R7 half-K ring-4, 32 barriers (61.9us): barrier count cost > quantum win
// Conclusion: this is the m97-class structure ceiling (~870 TF) at 2
// waves/SIMD; the remaining stall is the all-waves barrier drain (m233).
//
// Block->work map (verified R2): each XCD-round (32 co-resident blocks)
// covers a 4-mtile x 8-slab superblock: A 2MB + one Wz 2MB = 4MB per-XCD L2.
__global__ __launch_bounds__(512, 2) void qkv_gemm(
    const unsigned short* __restrict__ A,
    const unsigned short* __restrict__ W0, const unsigned short* __restrict__ W1,
    const unsigned short* __restrict__ W2,
    const float* __restrict__ b0, const float* __restrict__ b1,
    const float* __restrict__ b2,
    unsigned short* __restrict__ O0, unsigned short* __restrict__ O1,
    unsigned short* __restrict__ O2) {
  const int K = HID;
  const int N = HID;

  __shared__ __align__(16) unsigned short lds[3 * 24576];  // 3 x 48 KB

  const int tid = threadIdx.x;
  const int w = tid >> 6;          // 0..7
  const int lane = tid & 63;

  // XCD-local superblock mapping (verified R2: FETCH 49MB).
  const int bid = blockIdx.x;
  const int xcd = bid & 7;
  const int rr  = bid >> 3;        // 0..95
  const int sb  = rr >> 5;         // 0..2  XCD-round
  const int q   = rr & 31;
  const int sbid = xcd * 3 + sb;   // 0..23
  const int mg = sbid & 7;
  const int sg = sbid >> 3;
  const int mi   = mg * 4 + (q & 3);    // 0..31
  const int slab = sg * 8 + (q >> 2);   // 0..23 = z*8 + ni
  const int ni = slab & 7;
  const int z  = slab >> 3;
  const int m0 = mi << 8;          // *256
  const int n0 = ni << 7;          // *128

  const unsigned short* __restrict__ Wz = (z == 0) ? W0 : (z == 1) ? W1 : W2;
  const float* __restrict__ bias = (z == 0) ? b0 : (z == 1) ? b1 : b2;
  unsigned short* __restrict__ O = (z == 0) ? O0 : (z == 1) ? O1 : O2;

  // staging: per K-tile 48 KB = 48 segments of 1 KB (8 rows x 8 chunks of
  // 16B). Wave w owns segments w*6+u (u=0..5): segs 0..31 = A (256 rows),
  // segs 32..47 = B (128 rows). Lane l -> row lr=l>>3, LDS chunk l&7,
  // global chunk (l&7)^lr (XOR swizzle on the SOURCE side, LDS stays linear).
  const int lr = lane >> 3;
  const int ccs = (lane & 7) ^ lr;
  const unsigned short* gsrc[6];
  unsigned short* ldst[6];
  #pragma unroll
  for (int u = 0; u < 6; ++u) {
    const int seg = w * 6 + u;
    if (seg < 32) {
      gsrc[u] = A + (size_t)(m0 + seg * 8 + lr) * K + ccs * 8;
      ldst[u] = lds + seg * 512;
    } else {
      gsrc[u] = Wz + (size_t)(n0 + (seg - 32) * 8 + lr) * K + ccs * 8;
      ldst[u] = lds + 16384 + (seg - 32) * 512;
    }
  }

  // half-stage: 3 glds16 per call; 6 per K-tile per thread (vmcnt budget)
  auto stage3 = [&](int t, int h) {
    const int bofs = (t % 3) * 24576;
    const int ko = t * 64;
    #pragma unroll
    for (int u = h * 3; u < h * 3 + 3; ++u)
      glds16(gsrc[u] + ko, ldst[u] + bofs);
  };

  const int lrow = lane & 15;
  const int qd = lane >> 4;              // 0..3
  const int sw = lrow & 7;               // read-side swizzle key (row&7)

  floatx4 acc[4][4] = {};

  // prologue: tiles 0 and 1 in flight (12 loads/thread outstanding)
  stage3(0, 0); stage3(0, 1);
  stage3(1, 0); stage3(1, 1);

  for (int t = 0; t < 16; ++t) {
    // my ds_reads of tile t-1 fully drained before anyone may overwrite
    asm volatile("s_waitcnt lgkmcnt(0)" ::: "memory");
    // counted wait: tile t landed; tile t+1's 6 loads may stay in flight
    if (t < 15) asm volatile("s_waitcnt vmcnt(6)" ::: "memory");
    else        asm volatile("s_waitcnt vmcnt(0)" ::: "memory");
    __builtin_amdgcn_s_barrier();
    asm volatile("" ::: "memory");

    const unsigned short* Asb = lds + (t % 3) * 24576;
    const unsigned short* Bsb = Asb + 16384;
    const bool pf = (t + 2 < 16);

    #pragma unroll
    for (int kk = 0; kk < 2; ++kk) {
      if (pf) stage3(t + 2, kk);         // issue-early: hides under MFMA
      const int cp = (((kk << 2) | qd) ^ sw) << 3;  // swizzled chunk -> shorts
      short8 af[4], bf[4];
      #pragma unroll
      for (int im = 0; im < 4; ++im)
        af[im] = *(const short8*)(Asb + ((w & 3) * 64 + lrow + im * 16) * 64 + cp);
      #pragma unroll
      for (int in = 0; in < 4; ++in)
        bf[in] = *(const short8*)(Bsb + ((w >> 2) * 64 + lrow + in * 16) * 64 + cp);
      __builtin_amdgcn_s_setprio(1);
      #pragma unroll
      for (int im = 0; im < 4; ++im)
        #pragma unroll
        for (int in = 0; in < 4; ++in)
          acc[im][in] = __builtin_amdgcn_mfma_f32_16x16x32_bf16(af[im], bf[in], acc[im][in], 0, 0, 0);
      __builtin_amdgcn_s_setprio(0);
    }
  }

  // epilogue: C/D layout col = lane&15, row = quad*4 + r; write bf16
  #pragma unroll
  for (int im = 0; im < 4; ++im) {
    #pragma unroll
    for (int in = 0; in < 4; ++in) {
      const int col = n0 + (w >> 2) * 64 + in * 16 + lrow;
      const float bb = bias[col];
      #pragma unroll
      for (int r = 0; r < 4; ++r) {
        const int row = m0 + (w & 3) * 64 + im * 16 + (qd << 2) + r;
        O[(size_t)row * N + col] = f2bf_rne(acc[im][in][r] + bb);
      }
    }
  }
}

// ---------------- log-sparse attention ----------------
// 8 lanes per query (lane = 8 dims, 16 B bf16 loads), 32 queries per block.
// Two-phase register budget (K+scores+softmax, then V+accumulate).
// XCD-contiguous block swizzle: blocks for one head stay on one XCD's L2.
// Non-temporal output stores: out (32 MB, never re-read) must not evict the
// K/V gather working set from L2.
__global__ __launch_bounds__(256) void logsparse_attn(
    const unsigned short* __restrict__ Q, const unsigned short* __restrict__ K,
    const unsigned short* __restrict__ V, const float* __restrict__ mask,
    float* __restrict__ out) {
  // 4096 blocks -> XCD x gets contiguous logical range [x*512, (x+1)*512)
  const int bid = (blockIdx.x & 7) * 512 + (blockIdx.x >> 3);
  const int tid = threadIdx.x;
  const int l = tid & 7;
  const int qglob = bid * 32 + (tid >> 3);

  const int i = qglob & (S_LEN - 1);
  const int h = (qglob >> 11) & (NHEADS - 1);
  const int b = qglob >> 15;

  const size_t base = (size_t)b * S_LEN * HID + h * HDIM + l * 8;

  int js[12];
  js[0] = i;
  int nj = 1;
  for (int d = 1; d <= i; d <<= 1) js[nj++] = i - d;
  #pragma unroll
  for (int t = 0; t < 12; ++t)
    if (t >= nj) js[t] = i;   // clamp: valid row, zeroed after mask

  // ---- phase 1: K + Q + mask prefetch, scores, softmax ----
  short8 k8[12];
  #pragma unroll
  for (int t = 0; t < 12; ++t)
    k8[t] = *(const short8*)(K + base + (size_t)js[t] * HID);
  const short8 q8 = *(const short8*)(Q + base + (size_t)i * HID);
  float mk[12];
  #pragma unroll
  for (int t = 0; t < 12; ++t)
    mk[t] = mask[b * S_LEN + js[t]];

  float qf[8];
  #pragma unroll
  for (int e = 0; e < 8; ++e) qf[e] = bf2f((unsigned short)q8[e]);

  float s[12];
  #pragma unroll
  for (int t = 0; t < 12; ++t) {
    float p = 0.f;
    #pragma unroll
    for (int e = 0; e < 8; ++e) p += qf[e] * bf2f((unsigned short)k8[t][e]);
    p += __shfl_xor(p, 1, 64);
    p += __shfl_xor(p, 2, 64);
    p += __shfl_xor(p, 4, 64);
    s[t] = (t < nj) ? (p * 0.125f + mk[t]) : -1e30f;
  }

  float mx = s[0];
  #pragma unroll
  for (int t = 1; t < 12; ++t) mx = fmaxf(mx, s[t]);
  float lsum = 0.f;
  #pragma unroll
  for (int t = 0; t < 12; ++t) { s[t] = __expf(s[t] - mx); lsum += s[t]; }
  const float inv = 1.f / lsum;

  // ---- phase 2: V batch load + accumulate ----
  short8 v8[12];
  #pragma unroll
  for (int t = 0; t < 12; ++t)
    v8[t] = *(const short8*)(V + base + (size_t)js[t] * HID);

  float o[8] = {};
  #pragma unroll
  for (int t = 0; t < 12; ++t) {
    #pragma unroll
    for (int e = 0; e < 8; ++e) o[e] += s[t] * bf2f((unsigned short)v8[t][e]);
  }

  float* op = out + base + (size_t)i * HID;
  floatx4 o0 = {o[0] * inv, o[1] * inv, o[2] * inv, o[3] * inv};
  floatx4 o1 = {o[4] * inv, o[5] * inv, o[6] * inv, o[7] * inv};
  __builtin_nontemporal_store(o0, (floatx4*)op);
  __builtin_nontemporal_store(o1, (floatx4*)(op + 4));
}

// ---------------- launch ----------------
extern "C" void kernel_launch(void* const* d_in, const int* in_sizes, int n_in,
                              void* d_out, int out_size, void* d_ws, size_t ws_size,
                              hipStream_t stream) {
  const float* hs   = (const float*)d_in[0];
  const float* mask = (const float*)d_in[1];
  const float* Wq   = (const float*)d_in[2];
  const float* bq   = (const float*)d_in[3];
  const float* Wk   = (const float*)d_in[4];
  const float* bk   = (const float*)d_in[5];
  const float* Wv   = (const float*)d_in[6];
  const float* bv   = (const float*)d_in[7];
  float* out = (float*)d_out;

  // workspace layout (all bf16)
  unsigned short* hsb = (unsigned short*)d_ws;                  // M*H
  unsigned short* wqb = hsb + (size_t)M_ROWS * HID;             // H*H
  unsigned short* wkb = wqb + (size_t)HID * HID;
  unsigned short* wvb = wkb + (size_t)HID * HID;
  unsigned short* Qb = wvb + (size_t)HID * HID;                 // M*H
  unsigned short* Kb = Qb + (size_t)M_ROWS * HID;
  unsigned short* Vb = Kb + (size_t)M_ROWS * HID;

  // casts: one dispatch for hs + Wq + Wk + Wv
  {
    int quads = HS4 + 3 * W4;                 // 2883584
    cast_all<<<quads / 256, 256, 0, stream>>>(hs, Wq, Wk, Wv, hsb, wqb, wkb, wvb);
  }

  // QKV projections: 256x128 tiles -> 768 blocks = 3 rounds of 1 block/CU
  {
    qkv_gemm<<<768, 512, 0, stream>>>(hsb, wqb, wkb, wvb, bq, bk, bv, Qb, Kb, Vb);
  }

  // sparse attention: 32 queries per 256-thread block
  {
    int blocks = (BATCH * NHEADS * S_LEN) / 32;   // 4096
    logsparse_attn<<<blocks, 256, 0, stream>>>(Qb, Kb, Vb, mask, out);
  }
}